// Round 3
// baseline (661.470 us; speedup 1.0000x reference)
//
#include <hip/hip_runtime.h>
#include <math.h>

#define BB 8
#define DD 128
#define HWD 65536    // 256*256
#define NBLK 8192    // 524288 px / 64 px per block

__device__ __forceinline__ float warp_red_sum(float v) {
#pragma unroll
    for (int off = 32; off > 0; off >>= 1) v += __shfl_down(v, off, 64);
    return v;
}

// ws layout (floats): [0]=flag(int), [8..15]=loss_sum, [16..23]=cnt_sum, [24]=done counter
// Classify the raw byte layout of the (originally bool) mask buffer, and zero the
// accumulators for this launch. flag: 0=uint8, 1=int32, 2=float32, 3=int64
__global__ void detect_and_init(const uint4* __restrict__ mb, float* __restrict__ ws) {
    __shared__ int any_gt1, any_m4, any_m84;
    if (threadIdx.x == 0) { any_gt1 = 0; any_m4 = 0; any_m84 = 0; }
    if (threadIdx.x >= 8 && threadIdx.x <= 24) ws[threadIdx.x] = 0.f;  // sums + done ctr
    __syncthreads();
    int lg = 0, l4 = 0, l84 = 0;
#pragma unroll
    for (int it = 0; it < 16; ++it) {
        const int i = it * 256 + threadIdx.x;   // 4096 uint4 = 64 KB (min buffer 512 KB)
        uint4 w = mb[i];
        unsigned int anyw = w.x | w.y | w.z | w.w;
        if (anyw & 0xFEFEFEFEu) lg = 1;            // some byte > 1 -> float bits
        if (anyw & 0xFFFFFF00u) l4 = 1;            // nonzero byte at off%4 != 0 -> uint8
        if ((w.y | w.w) & 0xFFu) l84 = 1;          // nonzero byte at off%8 == 4 -> int32
    }
    if (lg)  atomicOr(&any_gt1, 1);
    if (l4)  atomicOr(&any_m4, 1);
    if (l84) atomicOr(&any_m84, 1);
    __syncthreads();
    if (threadIdx.x == 0) {
        int f;
        if (any_gt1)      f = 2;   // float32
        else if (any_m4)  f = 0;   // uint8/bool
        else if (any_m84) f = 1;   // int32
        else              f = 3;   // int64 (or all-false: interpretation-invariant)
        ((int*)ws)[0] = f;
    }
}

// 1024 threads = 16 waves. Wave w owns channels [8w, 8w+8); lane = pixel.
// Block covers 64 pixels x 128 channels. 16 data floats/thread -> register resident.
__global__ __launch_bounds__(1024, 8)
void pixel_dino_main(const float* __restrict__ s_feats,
                     const float* __restrict__ t_feats,
                     const float* __restrict__ center,
                     const void*  __restrict__ mask,
                     const float* __restrict__ orig_x,
                     float* __restrict__ ws,
                     float* __restrict__ out) {
    const float TAU_S_INV = 10.0f, TAU_T_INV = 25.0f, EPSN = 1e-12f;
    const int lane = threadIdx.x & 63;
    const int wave = threadIdx.x >> 6;             // 0..15
    const int b    = blockIdx.x >> 10;             // 1024 blocks per image
    const int hw   = ((blockIdx.x & 1023) << 6) + lane;
    const float* sp = s_feats + (size_t)b * (DD * HWD) + hw;
    const float* tp = t_feats + (size_t)b * (DD * HWD) + hw;
    const int d0 = wave * 8;

    float sl[8], tl[8];
    float ss = 0.f, tt = 0.f;
#pragma unroll
    for (int k = 0; k < 8; ++k) {
        sl[k] = sp[(size_t)(d0 + k) * HWD];
        tl[k] = tp[(size_t)(d0 + k) * HWD] - center[d0 + k];
        ss += sl[k] * sl[k];
        tt += tl[k] * tl[k];
    }
#pragma unroll
    for (int k = 0; k < 8; ++k) asm volatile("" : "+v"(sl[k]), "+v"(tl[k]));

    __shared__ float red[3][16][64];
    __shared__ float tot[3][64];
    red[0][wave][lane] = ss; red[1][wave][lane] = tt;
    __syncthreads();
    if (threadIdx.x < 128) {                 // 2 quantities x 64 pixels
        const int q = threadIdx.x >> 6, l = threadIdx.x & 63;
        float v = 0.f;
#pragma unroll
        for (int w = 0; w < 16; ++w) v += red[q][w][l];
        tot[q][l] = v;
    }
    __syncthreads();
    const float rs = TAU_S_INV / fmaxf(sqrtf(tot[0][lane]), EPSN);
    const float rt = TAU_T_INV / fmaxf(sqrtf(tot[1][lane]), EPSN);

    // No max-subtraction: |s_hat|/tau_s <= 10, |t_hat|/tau_t <= 25 -> exp fp32-safe.
    float eb = 0.f, ea = 0.f, eab = 0.f;
#pragma unroll
    for (int k = 0; k < 8; ++k) {
        const float bv = sl[k] * rs;
        const float av = tl[k] * rt;
        const float e2 = __expf(av);
        eb += __expf(bv);
        ea += e2;
        eab += e2 * bv;
    }
    __syncthreads();
    red[0][wave][lane] = eb; red[1][wave][lane] = ea; red[2][wave][lane] = eab;
    __syncthreads();
    if (threadIdx.x < 192) {                 // 3 quantities x 64 pixels
        const int q = threadIdx.x >> 6, l = threadIdx.x & 63;
        float v = 0.f;
#pragma unroll
        for (int w = 0; w < 16; ++w) v += red[q][w][l];
        tot[q][l] = v;
    }
    __syncthreads();

    if (wave == 0) {
        const float loss = __logf(tot[0][lane]) - tot[2][lane] / tot[1][lane];

        const int gidx = b * HWD + hw;
        const int flag = ((const int*)ws)[0];
        bool mval;
        if (flag == 0)      mval = ((const unsigned char*)mask)[gidx] != 0;
        else if (flag == 1) mval = ((const int*)mask)[gidx] != 0;
        else if (flag == 2) mval = ((const float*)mask)[gidx] != 0.f;
        else                mval = ((const long long*)mask)[gidx] != 0;
        const bool valid = (orig_x[gidx] != 0.f) && !mval;

        float l = valid ? loss : 0.f;
        float c = valid ? 1.f  : 0.f;
        l = warp_red_sum(l);
        c = warp_red_sum(c);
        if (lane == 0) {
            atomicAdd(&ws[8 + b], l);
            atomicAdd(&ws[16 + b], c);
        }
    }

    // Last block finalizes (done counter at ws[24], zeroed by detect_and_init).
    if (threadIdx.x == 0) {
        __threadfence();
        unsigned int old = atomicAdd((unsigned int*)(ws + 24), 1u);
        if (old == NBLK - 1) {
            __threadfence();
            volatile float* ls = ws + 8;
            volatile float* cs = ws + 16;
            float acc = 0.f, nnz = 0.f, totc = 0.f;
#pragma unroll
            for (int i = 0; i < BB; ++i) {
                float c = cs[i];
                totc += c;
                if (c > 0.f) { acc += ls[i] / c; nnz += 1.f; }
            }
            out[0] = (totc > 0.f) ? acc / fmaxf(nnz, 1.f) : 0.f;
        }
    }
}

extern "C" void kernel_launch(void* const* d_in, const int* in_sizes, int n_in,
                              void* d_out, int out_size, void* d_ws, size_t ws_size,
                              hipStream_t stream) {
    const float* s_feats = (const float*)d_in[0];
    const float* t_feats = (const float*)d_in[1];
    const float* center  = (const float*)d_in[2];
    const void*  mask    = d_in[3];
    const float* orig_x  = (const float*)d_in[4];
    float* ws = (float*)d_ws;

    detect_and_init<<<1, 256, 0, stream>>>((const uint4*)mask, ws);
    pixel_dino_main<<<NBLK, 1024, 0, stream>>>(s_feats, t_feats, center, mask,
                                               orig_x, ws, (float*)d_out);
}